// Round 2
// baseline (4917.512 us; speedup 1.0000x reference)
//
#include <hip/hip_runtime.h>

// SolarRNN: B=256, T=4096, F=16, H=64. Two fused GRU layers + online-softmax
// attention + MLP tail in ONE persistent kernel: block b = sequence b.
//
// R2: 8 waves/block (2 per SIMD), matvec-split instead of all-9-per-wave:
//  - even waves (g=0, slice v=w>>1): L1 gate partials {ar1,az1,an1,hn1,axp}
//    + an2 (= h1@Wi2n + x@(0.5 Wp@Wi2n)); 84 FMA/step, ~52 weight floats/lane.
//  - odd  waves (g=1, slice v=w>>1): L2 partials {ar2,az2,hn2} (wr2/wz2/wn2 +
//    u2r/u2z + x2r/x2z); full pointwise + online softmax; 88 FMA/step.
//  Per-lane weight footprint now fits ARCH VGPRs (R1 showed 132 VGPRs ->
//  unified-file AGPR traffic for the 160-float version); 2 waves/SIMD hide
//  post-barrier LDS latency + transcendental chains.
//  - Packed reduction: red[buf][acc][j][slice^(j&3)] -> conflict-free b32
//    writes AND conflict-free ds_read_b128 (sum is slot-permutation-invariant).
//  - Still ONE barrier per timestep, double-buffered; barrier counts match
//    across the two divergent wave roles (4097 each before the tail).

#define B_ 256
#define T_ 4096
#define F_ 16
#define H_ 64
#define L2E 1.4426950408889634f

__device__ __forceinline__ float rdlane(float v, int lane) {
    return __builtin_bit_cast(float, __builtin_amdgcn_readlane(__builtin_bit_cast(int, v), lane));
}
__device__ __forceinline__ float sigm(float x) {
    float e = __builtin_amdgcn_exp2f(-L2E * x);
    return __builtin_amdgcn_rcpf(1.0f + e);
}
__device__ __forceinline__ float tanh_(float x) {
    float e = __builtin_amdgcn_exp2f(2.0f * L2E * x);
    return 1.0f - 2.0f * __builtin_amdgcn_rcpf(1.0f + e);
}
#define SUM4(q) (((q).x + (q).y) + ((q).z + (q).w))

__launch_bounds__(512)
__attribute__((amdgpu_waves_per_eu(2, 2)))
__global__ void solar_rnn(const float* __restrict__ x,
                          const float* __restrict__ Wi1, const float* __restrict__ bi1,
                          const float* __restrict__ Whr1, const float* __restrict__ Whz1,
                          const float* __restrict__ Whn1, const float* __restrict__ bhn1,
                          const float* __restrict__ Wi2, const float* __restrict__ bi2,
                          const float* __restrict__ Whr2, const float* __restrict__ Whz2,
                          const float* __restrict__ Whn2, const float* __restrict__ bhn2,
                          const float* __restrict__ Wp, const float* __restrict__ bp,
                          const float* __restrict__ Wa,
                          const float* __restrict__ W1, const float* __restrict__ b1,
                          const float* __restrict__ W2, const float* __restrict__ b2,
                          const float* __restrict__ W3, const float* __restrict__ b3,
                          const float* __restrict__ W4, const float* __restrict__ b4,
                          float* __restrict__ out)
{
    const int b   = blockIdx.x;
    const int tid = threadIdx.x;
    const int w   = tid >> 6;    // wave 0..7
    const int j   = tid & 63;    // lane = output index
    const int g   = w & 1;       // 0 = L1-group, 1 = L2-group (interleaved -> one of each per SIMD)
    const int v   = w >> 1;      // k-slice 0..3 (rows [16v,16v+16))
    const int slot = v ^ (j & 3);// XOR slot: conflict-free writes, sum-invariant reads

    // accs: 0=ar1 1=az1 2=an1 3=hn1 4=axp 5=an2 6=ar2 7=az2 8=hn2
    __shared__ __align__(16) float red[2][9][H_][4];
    __shared__ float sm_a[128];
    __shared__ float sm_b[128];

    const float* xb = x + (size_t)b * T_ * F_;

    if (g == 0) {
        // ================= L1-group wave (slice v) =================
        float wr1[16], wz1[16], wn1[16], u2n[16];
        #pragma unroll
        for (int k = 0; k < 16; ++k) {
            const int row = 16 * v + k;
            wr1[k] = Whr1[row * H_ + j];
            wz1[k] = Whz1[row * H_ + j];
            wn1[k] = Whn1[row * H_ + j];
            u2n[k] = Wi2[row * 192 + 128 + j];
        }
        float w1r[4], w1z[4], w1n[4], wpv[4], x2n[4];
        #pragma unroll
        for (int kk = 0; kk < 4; ++kk) {
            const int row = 4 * v + kk;
            w1r[kk] = Wi1[row * 192 + j];
            w1z[kk] = Wi1[row * 192 + 64 + j];
            w1n[kk] = Wi1[row * 192 + 128 + j];
            wpv[kk] = Wp[row * H_ + j];
            float an = 0.f;
            for (int m = 0; m < H_; ++m)
                an = fmaf(Wp[row * H_ + m], Wi2[m * 192 + 128 + j], an);
            x2n[kk] = 0.5f * an;
        }
        const float bi1r = bi1[j], bi1z = bi1[64 + j], bi1n = bi1[128 + j], bh1 = bhn1[j];

        float h1 = 0.f;
        float4 xc = *(const float4*)(xb + (size_t)j * F_ + 4 * v);
        float4 xnx = *(const float4*)(xb + (size_t)(64 + j) * F_ + 4 * v);
        float cx0 = rdlane(xc.x, 0), cx1 = rdlane(xc.y, 0),
              cx2 = rdlane(xc.z, 0), cx3 = rdlane(xc.w, 0);

        // ---- P0: L1(0) partials (h=0) -> buf 0 ----
        {
            const float ar = fmaf(cx0, w1r[0], fmaf(cx1, w1r[1], fmaf(cx2, w1r[2], cx3 * w1r[3])));
            const float az = fmaf(cx0, w1z[0], fmaf(cx1, w1z[1], fmaf(cx2, w1z[2], cx3 * w1z[3])));
            const float an = fmaf(cx0, w1n[0], fmaf(cx1, w1n[1], fmaf(cx2, w1n[2], cx3 * w1n[3])));
            const float ax = fmaf(cx0, wpv[0], fmaf(cx1, wpv[1], fmaf(cx2, wpv[2], cx3 * wpv[3])));
            red[0][0][j][slot] = ar;
            red[0][1][j][slot] = az;
            red[0][2][j][slot] = an;
            red[0][3][j][slot] = 0.f;
            red[0][4][j][slot] = ax;
        }
        __syncthreads();                                   // barrier #0

        #pragma unroll 1
        for (int i = 0; i < T_; ++i) {                     // 4096 barriers
            const int pb = i & 1, qb = pb ^ 1;
            const int u = i + 1;                           // x index for L1(i+1)
            if ((u & 63) == 0) {
                xc = xnx;
                const int c = (u >> 6) + 1;
                if (c < T_ / 64)
                    xnx = *(const float4*)(xb + (size_t)(c * 64 + j) * F_ + 4 * v);
            }
            const int ul = u & 63;
            const float xu0 = rdlane(xc.x, ul), xu1 = rdlane(xc.y, ul),
                        xu2 = rdlane(xc.z, ul), xu3 = rdlane(xc.w, ul);

            const float4 q0 = *(const float4*)&red[pb][0][j][0];
            const float4 q1 = *(const float4*)&red[pb][1][j][0];
            const float4 q2 = *(const float4*)&red[pb][2][j][0];
            const float4 q3 = *(const float4*)&red[pb][3][j][0];
            const float r1 = sigm(SUM4(q0) + bi1r);
            const float z1 = sigm(SUM4(q1) + bi1z);
            const float n1 = tanh_((SUM4(q2) + bi1n) + r1 * (SUM4(q3) + bh1));
            h1 = n1 + z1 * (h1 - n1);

            float sH1[16];
            #pragma unroll
            for (int k = 0; k < 16; ++k) sH1[k] = rdlane(h1, 16 * v + k);

            // an2(i): uses x(i) (= cx) ; L1(i+1): uses x(i+1) (= xu)
            float an2 = fmaf(cx0, x2n[0], fmaf(cx1, x2n[1], fmaf(cx2, x2n[2], cx3 * x2n[3])));
            float ar1 = fmaf(xu0, w1r[0], fmaf(xu1, w1r[1], fmaf(xu2, w1r[2], xu3 * w1r[3])));
            float az1 = fmaf(xu0, w1z[0], fmaf(xu1, w1z[1], fmaf(xu2, w1z[2], xu3 * w1z[3])));
            float an1 = fmaf(xu0, w1n[0], fmaf(xu1, w1n[1], fmaf(xu2, w1n[2], xu3 * w1n[3])));
            float ax1 = fmaf(xu0, wpv[0], fmaf(xu1, wpv[1], fmaf(xu2, wpv[2], xu3 * wpv[3])));
            float hn1 = 0.f;
            #pragma unroll
            for (int k = 0; k < 16; ++k) {
                ar1 = fmaf(sH1[k], wr1[k], ar1);
                az1 = fmaf(sH1[k], wz1[k], az1);
                hn1 = fmaf(sH1[k], wn1[k], hn1);
                an2 = fmaf(sH1[k], u2n[k], an2);
            }
            red[qb][0][j][slot] = ar1;
            red[qb][1][j][slot] = az1;
            red[qb][2][j][slot] = an1;
            red[qb][3][j][slot] = hn1;
            red[qb][4][j][slot] = ax1;
            red[qb][5][j][slot] = an2;

            cx0 = xu0; cx1 = xu1; cx2 = xu2; cx3 = xu3;
            __syncthreads();
        }
    } else {
        // ================= L2-group wave (slice v) =================
        float wr2[16], wz2[16], wn2[16], u2r[16], u2z[16];
        #pragma unroll
        for (int k = 0; k < 16; ++k) {
            const int row = 16 * v + k;
            wr2[k] = Whr2[row * H_ + j];
            wz2[k] = Whz2[row * H_ + j];
            wn2[k] = Whn2[row * H_ + j];
            u2r[k] = Wi2[row * 192 + j];
            u2z[k] = Wi2[row * 192 + 64 + j];
        }
        float x2r[4], x2z[4];
        #pragma unroll
        for (int kk = 0; kk < 4; ++kk) {
            const int row = 4 * v + kk;
            float ar = 0.f, az = 0.f;
            for (int m = 0; m < H_; ++m) {
                const float wp = Wp[row * H_ + m];
                ar = fmaf(wp, Wi2[m * 192 + j],      ar);
                az = fmaf(wp, Wi2[m * 192 + 64 + j], az);
            }
            x2r[kk] = 0.5f * ar; x2z[kk] = 0.5f * az;
        }
        float cbr = 0.f, cbz = 0.f, cbn = 0.f;
        for (int m = 0; m < H_; ++m) {
            const float bpm = bp[m];
            cbr = fmaf(bpm, Wi2[m * 192 + j],       cbr);
            cbz = fmaf(bpm, Wi2[m * 192 + 64 + j],  cbz);
            cbn = fmaf(bpm, Wi2[m * 192 + 128 + j], cbn);
        }
        const float bi1r = bi1[j], bi1z = bi1[64 + j], bi1n = bi1[128 + j], bh1 = bhn1[j];
        const float bb2r = bi2[j]        + 0.5f * cbr;
        const float bb2z = bi2[64 + j]   + 0.5f * cbz;
        const float bb2n = bi2[128 + j]  + 0.5f * cbn;
        const float bh2  = bhn2[j];
        const float bpj  = bp[j], waj = Wa[j];

        float h1 = 0.f, h2 = 0.f, o1p = 0.f;
        float am = -3.0e38f, al = 0.f, aa = 0.f;
        float4 xc = *(const float4*)(xb + (size_t)j * F_ + 4 * v);
        float4 xnx = *(const float4*)(xb + (size_t)(64 + j) * F_ + 4 * v);

        __syncthreads();                                   // barrier #0 (match P0)

        // ---- peeled i = 0: h1(0), o1(0); write {ar2,az2,hn2}(0) (h2(-1)=0) ----
        {
            const float xt0 = rdlane(xc.x, 0), xt1 = rdlane(xc.y, 0),
                        xt2 = rdlane(xc.z, 0), xt3 = rdlane(xc.w, 0);
            const float4 q0 = *(const float4*)&red[0][0][j][0];
            const float4 q1 = *(const float4*)&red[0][1][j][0];
            const float4 q2 = *(const float4*)&red[0][2][j][0];
            const float4 q3 = *(const float4*)&red[0][3][j][0];
            const float4 q4 = *(const float4*)&red[0][4][j][0];
            const float r1 = sigm(SUM4(q0) + bi1r);
            const float z1 = sigm(SUM4(q1) + bi1z);
            const float n1 = tanh_((SUM4(q2) + bi1n) + r1 * (SUM4(q3) + bh1));
            h1 = n1 + z1 * (h1 - n1);
            o1p = h1 + 0.5f * (SUM4(q4) + bpj);
            float sH1[16];
            #pragma unroll
            for (int k = 0; k < 16; ++k) sH1[k] = rdlane(h1, 16 * v + k);
            float ar2 = fmaf(xt0, x2r[0], fmaf(xt1, x2r[1], fmaf(xt2, x2r[2], xt3 * x2r[3])));
            float az2 = fmaf(xt0, x2z[0], fmaf(xt1, x2z[1], fmaf(xt2, x2z[2], xt3 * x2z[3])));
            #pragma unroll
            for (int k = 0; k < 16; ++k) {
                ar2 = fmaf(sH1[k], u2r[k], ar2);
                az2 = fmaf(sH1[k], u2z[k], az2);
            }
            red[1][6][j][slot] = ar2;
            red[1][7][j][slot] = az2;
            red[1][8][j][slot] = 0.f;
            __syncthreads();                               // barrier (i=0)
        }

        #pragma unroll 1
        for (int i = 1; i < T_; ++i) {                     // 4095 barriers
            const int pb = i & 1, qb = pb ^ 1;
            if ((i & 63) == 0) {
                xc = xnx;
                const int c = (i >> 6) + 1;
                if (c < T_ / 64)
                    xnx = *(const float4*)(xb + (size_t)(c * 64 + j) * F_ + 4 * v);
            }
            const int ul = i & 63;
            const float xt0 = rdlane(xc.x, ul), xt1 = rdlane(xc.y, ul),
                        xt2 = rdlane(xc.z, ul), xt3 = rdlane(xc.w, ul);

            const float4 q0 = *(const float4*)&red[pb][0][j][0];
            const float4 q1 = *(const float4*)&red[pb][1][j][0];
            const float4 q2 = *(const float4*)&red[pb][2][j][0];
            const float4 q3 = *(const float4*)&red[pb][3][j][0];
            const float4 q4 = *(const float4*)&red[pb][4][j][0];
            const float4 q5 = *(const float4*)&red[pb][5][j][0];
            const float4 q6 = *(const float4*)&red[pb][6][j][0];
            const float4 q7 = *(const float4*)&red[pb][7][j][0];
            const float4 q8 = *(const float4*)&red[pb][8][j][0];

            // ---- h2(i-1) + softmax score ----
            const float r2 = sigm(SUM4(q6) + bb2r);
            const float z2 = sigm(SUM4(q7) + bb2z);
            const float n2 = tanh_((SUM4(q5) + bb2n) + r2 * (SUM4(q8) + bh2));
            h2 = n2 + z2 * (h2 - n2);
            const float o2 = h2 + 0.5f * o1p;
            float p = o2 * waj;
            #pragma unroll
            for (int mask = 32; mask >= 1; mask >>= 1) p += __shfl_xor(p, mask);

            // ---- h1(i), o1(i) ----
            const float r1 = sigm(SUM4(q0) + bi1r);
            const float z1 = sigm(SUM4(q1) + bi1z);
            const float n1 = tanh_((SUM4(q2) + bi1n) + r1 * (SUM4(q3) + bh1));
            h1 = n1 + z1 * (h1 - n1);
            const float o1 = h1 + 0.5f * (SUM4(q4) + bpj);

            float sH1[16], sH2[16];
            #pragma unroll
            for (int k = 0; k < 16; ++k) {
                sH1[k] = rdlane(h1, 16 * v + k);
                sH2[k] = rdlane(h2, 16 * v + k);
            }
            // ---- {ar2,az2,hn2}(i) partials ----
            float ar2 = fmaf(xt0, x2r[0], fmaf(xt1, x2r[1], fmaf(xt2, x2r[2], xt3 * x2r[3])));
            float az2 = fmaf(xt0, x2z[0], fmaf(xt1, x2z[1], fmaf(xt2, x2z[2], xt3 * x2z[3])));
            float hn2 = 0.f;
            #pragma unroll
            for (int k = 0; k < 16; ++k) {
                ar2 = fmaf(sH1[k], u2r[k], ar2);
                az2 = fmaf(sH1[k], u2z[k], az2);
                ar2 = fmaf(sH2[k], wr2[k], ar2);
                az2 = fmaf(sH2[k], wz2[k], az2);
                hn2 = fmaf(sH2[k], wn2[k], hn2);
            }
            red[qb][6][j][slot] = ar2;
            red[qb][7][j][slot] = az2;
            red[qb][8][j][slot] = hn2;

            // ---- online-softmax update (step i-1) ----
            const float mn = fmaxf(am, p);
            const float ca = __builtin_amdgcn_exp2f((am - mn) * L2E);
            const float ce = __builtin_amdgcn_exp2f((p  - mn) * L2E);
            al = fmaf(al, ca, ce);
            aa = fmaf(aa, ca, ce * o2);
            am = mn;

            o1p = o1;
            __syncthreads();
        }

        // ---- epilogue: h2(T-1) + final softmax contribution ----
        {
            const float4 q5 = *(const float4*)&red[0][5][j][0];
            const float4 q6 = *(const float4*)&red[0][6][j][0];
            const float4 q7 = *(const float4*)&red[0][7][j][0];
            const float4 q8 = *(const float4*)&red[0][8][j][0];
            const float r2 = sigm(SUM4(q6) + bb2r);
            const float z2 = sigm(SUM4(q7) + bb2z);
            const float n2 = tanh_((SUM4(q5) + bb2n) + r2 * (SUM4(q8) + bh2));
            h2 = n2 + z2 * (h2 - n2);
            const float o2 = h2 + 0.5f * o1p;
            float p = o2 * waj;
            #pragma unroll
            for (int mask = 32; mask >= 1; mask >>= 1) p += __shfl_xor(p, mask);
            const float mn = fmaxf(am, p);
            const float ca = __builtin_amdgcn_exp2f((am - mn) * L2E);
            const float ce = __builtin_amdgcn_exp2f((p  - mn) * L2E);
            al = fmaf(al, ca, ce);
            aa = fmaf(aa, ca, ce * o2);
        }
        if (w == 1) sm_a[j] = aa / al;   // attended vector
    }

    __syncthreads();

    // ---- MLP tail (once per block) ----
    float v1 = 0.f;
    if (tid < 128) {
        float a = b1[tid];
        for (int k = 0; k < 64; ++k) a = fmaf(sm_a[k], W1[k * 128 + tid], a);
        v1 = fmaxf(a, 0.f);
    }
    __syncthreads();
    if (tid < 128) sm_b[tid] = v1;
    __syncthreads();
    if (tid < 64) {
        float a = b2[tid];
        for (int k = 0; k < 128; ++k) a = fmaf(sm_b[k], W2[k * 64 + tid], a);
        sm_a[tid] = fmaxf(a, 0.f);
    }
    __syncthreads();
    if (tid < 32) {
        float a = b3[tid];
        for (int k = 0; k < 64; ++k) a = fmaf(sm_a[k], W3[k * 32 + tid], a);
        sm_b[tid] = fmaxf(a, 0.f);
    }
    __syncthreads();
    if (tid < 2) {
        float a = b4[tid];
        for (int k = 0; k < 32; ++k) a = fmaf(sm_b[k], W4[k * 2 + tid], a);
        out[b * 2 + tid] = a;
    }
}

extern "C" void kernel_launch(void* const* d_in, const int* in_sizes, int n_in,
                              void* d_out, int out_size, void* d_ws, size_t ws_size,
                              hipStream_t stream) {
    const float* x    = (const float*)d_in[0];
    const float* Wi1  = (const float*)d_in[1];
    const float* bi1  = (const float*)d_in[2];
    const float* Whr1 = (const float*)d_in[3];
    const float* Whz1 = (const float*)d_in[4];
    const float* Whn1 = (const float*)d_in[5];
    const float* bhn1 = (const float*)d_in[6];
    const float* Wi2  = (const float*)d_in[7];
    const float* bi2  = (const float*)d_in[8];
    const float* Whr2 = (const float*)d_in[9];
    const float* Whz2 = (const float*)d_in[10];
    const float* Whn2 = (const float*)d_in[11];
    const float* bhn2 = (const float*)d_in[12];
    const float* Wp   = (const float*)d_in[13];
    const float* bp   = (const float*)d_in[14];
    const float* Wa   = (const float*)d_in[15];
    // d_in[16] = ba: softmax shift-invariant, unused
    const float* W1   = (const float*)d_in[17];
    const float* b1   = (const float*)d_in[18];
    const float* W2   = (const float*)d_in[19];
    const float* b2   = (const float*)d_in[20];
    const float* W3   = (const float*)d_in[21];
    const float* b3   = (const float*)d_in[22];
    const float* W4   = (const float*)d_in[23];
    const float* b4   = (const float*)d_in[24];

    solar_rnn<<<dim3(B_), dim3(512), 0, stream>>>(
        x, Wi1, bi1, Whr1, Whz1, Whn1, bhn1,
        Wi2, bi2, Whr2, Whz2, Whn2, bhn2,
        Wp, bp, Wa, W1, b1, W2, b2, W3, b3, W4, b4,
        (float*)d_out);
}

// Round 3
// 3341.270 us; speedup vs baseline: 1.4717x; 1.4717x over previous
//
#include <hip/hip_runtime.h>

// SolarRNN: B=256, T=4096, F=16, H=64. Two fused GRU layers + online-softmax
// attention + MLP tail in ONE persistent kernel: block b = sequence b.
//
// R3: 4 waves, 1 barrier/step (R1 schedule) + QUARTER-DENSITY reduction:
//  - Partial reads: lane j reads ONE word per acc at [acc][64v+j] (stride-1,
//    conflict-free, 9 b32/wave vs R1's 36); a 2-step DPP quad_perm add gives
//    each quad of lanes the full 4-slice sum for output o(j)=16v+(j>>2).
//  - All pointwise state (h1,h2,o1,o2,softmax acc, biases) is quarter-density
//    (indexed by o(j)); the FMA partials block stays full-density (lane j =
//    output col j), fed by 16+16 readlanes taken from lanes 4m.
//  - Softmax score reduce: 6 DPP row-adds (VALU) instead of 6 dependent
//    ds_bpermute (~300cy chain); cross-wave combine via 4 LDS words read one
//    step later (extra +1 pipeline skew, resolved in epilogue).
//  - Partial writes at slot (v+(j>>3))&3: bijective per output, <=2-way bank
//    aliasing (free), fixing R2's 8-way write conflicts.

#define B_ 256
#define T_ 4096
#define F_ 16
#define H_ 64
#define L2E 1.4426950408889634f

__device__ __forceinline__ float rdlane(float v, int lane) {
    return __builtin_bit_cast(float, __builtin_amdgcn_readlane(__builtin_bit_cast(int, v), lane));
}
__device__ __forceinline__ float sigm(float x) {
    float e = __builtin_amdgcn_exp2f(-L2E * x);
    return __builtin_amdgcn_rcpf(1.0f + e);
}
__device__ __forceinline__ float tanh_(float x) {
    float e = __builtin_amdgcn_exp2f(2.0f * L2E * x);
    return 1.0f - 2.0f * __builtin_amdgcn_rcpf(1.0f + e);
}

#define DPPADD(x, ctrl) \
    ((x) + __builtin_bit_cast(float, __builtin_amdgcn_update_dpp( \
        0, __builtin_bit_cast(int, (x)), (ctrl), 0xF, 0xF, true)))

// sum across each quad of lanes (4 slots); result in all 4 lanes of the quad
__device__ __forceinline__ float qsum(float x) {
    float s = DPPADD(x, 0xB1);   // quad_perm [1,0,3,2]
    return DPPADD(s, 0x4E);      // quad_perm [2,3,0,1]
}
// full wave64 sum; total lands in lane 63
__device__ __forceinline__ float wred(float x) {
    x = DPPADD(x, 0x111);        // row_shr:1
    x = DPPADD(x, 0x112);        // row_shr:2
    x = DPPADD(x, 0x114);        // row_shr:4
    x = DPPADD(x, 0x118);        // row_shr:8
    x = DPPADD(x, 0x142);        // row_bcast:15
    x = DPPADD(x, 0x143);        // row_bcast:31
    return x;
}

__launch_bounds__(256, 1)
__global__ void solar_rnn(const float* __restrict__ x,
                          const float* __restrict__ Wi1, const float* __restrict__ bi1,
                          const float* __restrict__ Whr1, const float* __restrict__ Whz1,
                          const float* __restrict__ Whn1, const float* __restrict__ bhn1,
                          const float* __restrict__ Wi2, const float* __restrict__ bi2,
                          const float* __restrict__ Whr2, const float* __restrict__ Whz2,
                          const float* __restrict__ Whn2, const float* __restrict__ bhn2,
                          const float* __restrict__ Wp, const float* __restrict__ bp,
                          const float* __restrict__ Wa,
                          const float* __restrict__ W1, const float* __restrict__ b1,
                          const float* __restrict__ W2, const float* __restrict__ b2,
                          const float* __restrict__ W3, const float* __restrict__ b3,
                          const float* __restrict__ W4, const float* __restrict__ b4,
                          float* __restrict__ out)
{
    const int b   = blockIdx.x;
    const int tid = threadIdx.x;
    const int v   = tid >> 6;        // wave 0..3 = k-slice (rows [16v,16v+16))
    const int j   = tid & 63;        // lane: FMA block -> output col j
    const int oj  = 16 * v + (j >> 2);  // quarter-density output index

    // planes 0-8: partials, word = output*4 + slot_phys; plane 9: p-partials[4]
    __shared__ float red[2][10][256];
    __shared__ float sm_a[128];
    __shared__ float sm_b[128];

    const int wslot = (v + (j >> 3)) & 3;    // bijective per output, <=2-way banks
    const int widx  = 4 * j + wslot;
    const int ridx  = 64 * v + j;            // = o(j)*4 + (j&3), stride-1

    // ---- per-lane weight slices (column j, rows [16v,16v+16)) ----
    float wr1[16], wz1[16], wn1[16];
    float wr2[16], wz2[16], wn2[16];
    float u2r[16], u2z[16], u2n[16];
    #pragma unroll
    for (int k = 0; k < 16; ++k) {
        const int row = 16 * v + k;
        wr1[k] = Whr1[row * H_ + j];
        wz1[k] = Whz1[row * H_ + j];
        wn1[k] = Whn1[row * H_ + j];
        wr2[k] = Whr2[row * H_ + j];
        wz2[k] = Whz2[row * H_ + j];
        wn2[k] = Whn2[row * H_ + j];
        u2r[k] = Wi2[row * 192 + j];
        u2z[k] = Wi2[row * 192 + 64 + j];
        u2n[k] = Wi2[row * 192 + 128 + j];
    }
    float w1r[4], w1z[4], w1n[4], wpv[4], x2r[4], x2z[4], x2n[4];
    #pragma unroll
    for (int kk = 0; kk < 4; ++kk) {
        const int row = 4 * v + kk;
        w1r[kk] = Wi1[row * 192 + j];
        w1z[kk] = Wi1[row * 192 + 64 + j];
        w1n[kk] = Wi1[row * 192 + 128 + j];
        wpv[kk] = Wp[row * H_ + j];
        float ar = 0.f, az = 0.f, an = 0.f;
        for (int m = 0; m < H_; ++m) {
            const float wp = Wp[row * H_ + m];
            ar = fmaf(wp, Wi2[m * 192 + j],       ar);
            az = fmaf(wp, Wi2[m * 192 + 64 + j],  az);
            an = fmaf(wp, Wi2[m * 192 + 128 + j], an);
        }
        x2r[kk] = 0.5f * ar; x2z[kk] = 0.5f * az; x2n[kk] = 0.5f * an;
    }
    // ---- quarter-density (oj-indexed) biases ----
    float cbr = 0.f, cbz = 0.f, cbn = 0.f;
    for (int m = 0; m < H_; ++m) {
        const float bpm = bp[m];
        cbr = fmaf(bpm, Wi2[m * 192 + oj],       cbr);
        cbz = fmaf(bpm, Wi2[m * 192 + 64 + oj],  cbz);
        cbn = fmaf(bpm, Wi2[m * 192 + 128 + oj], cbn);
    }
    const float b1r = bi1[oj], b1z = bi1[64 + oj], b1n = bi1[128 + oj], bh1o = bhn1[oj];
    const float bb2r = bi2[oj]       + 0.5f * cbr;
    const float bb2z = bi2[64 + oj]  + 0.5f * cbz;
    const float bb2n = bi2[128 + oj] + 0.5f * cbn;
    const float bh2o = bhn2[oj];
    const float bpo  = bp[oj], wao = Wa[oj];
    // ba: softmax shift-invariant, skipped.

    float h1 = 0.f, h2 = 0.f, o1p = 0.f, o2a = 0.f;   // quarter-density state
    float am = -3.0e38f, al = 0.f, aa = 0.f;
    float sH1[16], sH2[16];
    #pragma unroll
    for (int k = 0; k < 16; ++k) { sH1[k] = 0.f; sH2[k] = 0.f; }

    const float* xb = x + (size_t)b * T_ * F_;
    float4 xq_cur  = *(const float4*)(xb + ((size_t)j * F_ + 4 * v));
    float4 xq_next = *(const float4*)(xb + ((size_t)(64 + j) * F_ + 4 * v));

    float cx0, cx1, cx2, cx3;   // x(t) scalars carried across iterations

    // ---- pro0: L1 x-partials(0) -> buf0 ----
    {
        const float a0 = rdlane(xq_cur.x, 0), a1 = rdlane(xq_cur.y, 0),
                    a2 = rdlane(xq_cur.z, 0), a3 = rdlane(xq_cur.w, 0);
        red[0][0][widx] = fmaf(a0, w1r[0], fmaf(a1, w1r[1], fmaf(a2, w1r[2], a3 * w1r[3])));
        red[0][1][widx] = fmaf(a0, w1z[0], fmaf(a1, w1z[1], fmaf(a2, w1z[2], a3 * w1z[3])));
        red[0][2][widx] = fmaf(a0, w1n[0], fmaf(a1, w1n[1], fmaf(a2, w1n[2], a3 * w1n[3])));
        red[0][3][widx] = 0.f;
        red[0][4][widx] = fmaf(a0, wpv[0], fmaf(a1, wpv[1], fmaf(a2, wpv[2], a3 * wpv[3])));
        cx0 = a0; cx1 = a1; cx2 = a2; cx3 = a3;
    }
    __syncthreads();

    // ---- pro1 (peeled step 0): h1(0); write L2(0)+L1(1) -> buf1 ----
    {
        float g0 = qsum(red[0][0][ridx]);
        float g1 = qsum(red[0][1][ridx]);
        float g2 = qsum(red[0][2][ridx]);
        float g3 = qsum(red[0][3][ridx]);
        float g4 = qsum(red[0][4][ridx]);
        const float r1 = sigm(g0 + b1r);
        const float z1 = sigm(g1 + b1z);
        const float n1 = tanh_((g2 + b1n) + r1 * (g3 + bh1o));
        h1 = n1 + z1 * (h1 - n1);
        o1p = h1 + 0.5f * (g4 + bpo);
        #pragma unroll
        for (int k = 0; k < 16; ++k) sH1[k] = rdlane(h1, 4 * k);

        const float xn0 = rdlane(xq_cur.x, 1), xn1 = rdlane(xq_cur.y, 1),
                    xn2 = rdlane(xq_cur.z, 1), xn3 = rdlane(xq_cur.w, 1);
        // L2(0) partials (h2(-1)=0)
        float ar2 = fmaf(cx0, x2r[0], fmaf(cx1, x2r[1], fmaf(cx2, x2r[2], cx3 * x2r[3])));
        float az2 = fmaf(cx0, x2z[0], fmaf(cx1, x2z[1], fmaf(cx2, x2z[2], cx3 * x2z[3])));
        float an2 = fmaf(cx0, x2n[0], fmaf(cx1, x2n[1], fmaf(cx2, x2n[2], cx3 * x2n[3])));
        #pragma unroll
        for (int k = 0; k < 16; ++k) {
            ar2 = fmaf(sH1[k], u2r[k], ar2);
            az2 = fmaf(sH1[k], u2z[k], az2);
            an2 = fmaf(sH1[k], u2n[k], an2);
        }
        red[1][5][widx] = ar2;
        red[1][6][widx] = az2;
        red[1][7][widx] = an2;
        red[1][8][widx] = 0.f;
        // L1(1) partials
        float ar1 = fmaf(xn0, w1r[0], fmaf(xn1, w1r[1], fmaf(xn2, w1r[2], xn3 * w1r[3])));
        float az1 = fmaf(xn0, w1z[0], fmaf(xn1, w1z[1], fmaf(xn2, w1z[2], xn3 * w1z[3])));
        float an1 = fmaf(xn0, w1n[0], fmaf(xn1, w1n[1], fmaf(xn2, w1n[2], xn3 * w1n[3])));
        float ax1 = fmaf(xn0, wpv[0], fmaf(xn1, wpv[1], fmaf(xn2, wpv[2], xn3 * wpv[3])));
        float hn1 = 0.f;
        #pragma unroll
        for (int k = 0; k < 16; ++k) {
            ar1 = fmaf(sH1[k], wr1[k], ar1);
            az1 = fmaf(sH1[k], wz1[k], az1);
            hn1 = fmaf(sH1[k], wn1[k], hn1);
        }
        red[1][0][widx] = ar1;
        red[1][1][widx] = az1;
        red[1][2][widx] = an1;
        red[1][3][widx] = hn1;
        red[1][4][widx] = ax1;
        cx0 = xn0; cx1 = xn1; cx2 = xn2; cx3 = xn3;
    }
    __syncthreads();

    // ---- main loop: iter t reduces L2(t-1)+L1(t), writes L2(t)+L1(t+1),
    //      softmax update for step t-2 (p-partials arrive 1 step late) ----
    #pragma unroll 1
    for (int t = 1; t < T_; ++t) {
        const int pb = t & 1, qb = pb ^ 1;
        const int u = t + 1;
        if ((u & 63) == 0) {
            xq_cur = xq_next;
            const int c = (u >> 6) + 1;
            if (c < T_ / 64)
                xq_next = *(const float4*)(xb + (size_t)(c * 64 + j) * F_ + 4 * v);
        }
        const int ul = u & 63;
        const float xn0 = rdlane(xq_cur.x, ul), xn1 = rdlane(xq_cur.y, ul),
                    xn2 = rdlane(xq_cur.z, ul), xn3 = rdlane(xq_cur.w, ul);

        const float* rp = &red[pb][0][0];
        float g0 = rp[0 * 256 + ridx], g1 = rp[1 * 256 + ridx], g2 = rp[2 * 256 + ridx];
        float g3 = rp[3 * 256 + ridx], g4 = rp[4 * 256 + ridx], g5 = rp[5 * 256 + ridx];
        float g6 = rp[6 * 256 + ridx], g7 = rp[7 * 256 + ridx], g8 = rp[8 * 256 + ridx];
        float gp = rp[9 * 256 + (j & 3)];
        g0 = qsum(g0); g1 = qsum(g1); g2 = qsum(g2); g3 = qsum(g3); g4 = qsum(g4);
        g5 = qsum(g5); g6 = qsum(g6); g7 = qsum(g7); g8 = qsum(g8); gp = qsum(gp);

        // softmax update for step t-2 (o2a = o2(t-2), gp = its score partials)
        if (t >= 2) {
            const float p  = 0.25f * gp;
            const float mn = fmaxf(am, p);
            const float ca = __builtin_amdgcn_exp2f((am - mn) * L2E);
            const float ce = __builtin_amdgcn_exp2f((p  - mn) * L2E);
            al = fmaf(al, ca, ce);
            aa = fmaf(aa, ca, ce * o2a);
            am = mn;
        }

        // ---- h2(t-1) + score partial ----
        const float r2 = sigm(g5 + bb2r);
        const float z2 = sigm(g6 + bb2z);
        const float n2 = tanh_((g7 + bb2n) + r2 * (g8 + bh2o));
        h2 = n2 + z2 * (h2 - n2);
        const float o2 = h2 + 0.5f * o1p;
        float ps = wred(o2 * wao);
        if (j == 63) red[qb][9][v] = ps;
        o2a = o2;
        #pragma unroll
        for (int k = 0; k < 16; ++k) sH2[k] = rdlane(h2, 4 * k);

        // ---- h1(t) ----
        const float r1 = sigm(g0 + b1r);
        const float z1 = sigm(g1 + b1z);
        const float n1 = tanh_((g2 + b1n) + r1 * (g3 + bh1o));
        h1 = n1 + z1 * (h1 - n1);
        o1p = h1 + 0.5f * (g4 + bpo);
        #pragma unroll
        for (int k = 0; k < 16; ++k) sH1[k] = rdlane(h1, 4 * k);

        // ---- FMA partials: L2(t) + L1(t+1) -> red[qb] ----
        float ar2 = fmaf(cx0, x2r[0], fmaf(cx1, x2r[1], fmaf(cx2, x2r[2], cx3 * x2r[3])));
        float az2 = fmaf(cx0, x2z[0], fmaf(cx1, x2z[1], fmaf(cx2, x2z[2], cx3 * x2z[3])));
        float an2 = fmaf(cx0, x2n[0], fmaf(cx1, x2n[1], fmaf(cx2, x2n[2], cx3 * x2n[3])));
        float hn2 = 0.f;
        #pragma unroll
        for (int k = 0; k < 16; ++k) {
            ar2 = fmaf(sH2[k], wr2[k], ar2);
            az2 = fmaf(sH2[k], wz2[k], az2);
            hn2 = fmaf(sH2[k], wn2[k], hn2);
        }
        #pragma unroll
        for (int k = 0; k < 16; ++k) {
            ar2 = fmaf(sH1[k], u2r[k], ar2);
            az2 = fmaf(sH1[k], u2z[k], az2);
            an2 = fmaf(sH1[k], u2n[k], an2);
        }
        float* wp_ = &red[qb][0][0];
        wp_[5 * 256 + widx] = ar2;
        wp_[6 * 256 + widx] = az2;
        wp_[7 * 256 + widx] = an2;
        wp_[8 * 256 + widx] = hn2;

        float ar1 = fmaf(xn0, w1r[0], fmaf(xn1, w1r[1], fmaf(xn2, w1r[2], xn3 * w1r[3])));
        float az1 = fmaf(xn0, w1z[0], fmaf(xn1, w1z[1], fmaf(xn2, w1z[2], xn3 * w1z[3])));
        float an1 = fmaf(xn0, w1n[0], fmaf(xn1, w1n[1], fmaf(xn2, w1n[2], xn3 * w1n[3])));
        float ax1 = fmaf(xn0, wpv[0], fmaf(xn1, wpv[1], fmaf(xn2, wpv[2], xn3 * wpv[3])));
        float hn1 = 0.f;
        #pragma unroll
        for (int k = 0; k < 16; ++k) {
            ar1 = fmaf(sH1[k], wr1[k], ar1);
            az1 = fmaf(sH1[k], wz1[k], az1);
            hn1 = fmaf(sH1[k], wn1[k], hn1);
        }
        wp_[0 * 256 + widx] = ar1;
        wp_[1 * 256 + widx] = az1;
        wp_[2 * 256 + widx] = an1;
        wp_[3 * 256 + widx] = hn1;
        wp_[4 * 256 + widx] = ax1;

        cx0 = xn0; cx1 = xn1; cx2 = xn2; cx3 = xn3;
        __syncthreads();
    }

    // ---- epilogue: pending steps T-2 and T-1 ----
    {
        // last iter (t=T-1, odd) wrote to buf 0
        const float* rp = &red[0][0][0];
        float g5 = qsum(rp[5 * 256 + ridx]);
        float g6 = qsum(rp[6 * 256 + ridx]);
        float g7 = qsum(rp[7 * 256 + ridx]);
        float g8 = qsum(rp[8 * 256 + ridx]);
        float gp = qsum(rp[9 * 256 + (j & 3)]);
        // softmax update (T-2): o2a = o2(T-2)
        {
            const float p  = 0.25f * gp;
            const float mn = fmaxf(am, p);
            const float ca = __builtin_amdgcn_exp2f((am - mn) * L2E);
            const float ce = __builtin_amdgcn_exp2f((p  - mn) * L2E);
            al = fmaf(al, ca, ce);
            aa = fmaf(aa, ca, ce * o2a);
            am = mn;
        }
        // h2(T-1)
        const float r2 = sigm(g5 + bb2r);
        const float z2 = sigm(g6 + bb2z);
        const float n2 = tanh_((g7 + bb2n) + r2 * (g8 + bh2o));
        h2 = n2 + z2 * (h2 - n2);
        const float o2 = h2 + 0.5f * o1p;
        float ps = wred(o2 * wao);
        if (j == 63) red[1][9][v] = ps;
        __syncthreads();
        float gq = qsum(red[1][9][j & 3]);
        {
            const float p  = 0.25f * gq;
            const float mn = fmaxf(am, p);
            const float ca = __builtin_amdgcn_exp2f((am - mn) * L2E);
            const float ce = __builtin_amdgcn_exp2f((p  - mn) * L2E);
            al = fmaf(al, ca, ce);
            aa = fmaf(aa, ca, ce * o2);
            am = mn;
        }
    }

    // ---- attended vector (quarter-density -> sm_a) + MLP tail ----
    if ((j & 3) == 0) sm_a[oj] = aa / al;
    __syncthreads();

    float v1 = 0.f;
    if (tid < 128) {
        float a = b1[tid];
        for (int k = 0; k < 64; ++k) a = fmaf(sm_a[k], W1[k * 128 + tid], a);
        v1 = fmaxf(a, 0.f);
    }
    __syncthreads();
    if (tid < 128) sm_b[tid] = v1;
    __syncthreads();
    if (tid < 64) {
        float a = b2[tid];
        for (int k = 0; k < 128; ++k) a = fmaf(sm_b[k], W2[k * 64 + tid], a);
        sm_a[tid] = fmaxf(a, 0.f);
    }
    __syncthreads();
    if (tid < 32) {
        float a = b3[tid];
        for (int k = 0; k < 64; ++k) a = fmaf(sm_a[k], W3[k * 32 + tid], a);
        sm_b[tid] = fmaxf(a, 0.f);
    }
    __syncthreads();
    if (tid < 2) {
        float a = b4[tid];
        for (int k = 0; k < 32; ++k) a = fmaf(sm_b[k], W4[k * 2 + tid], a);
        out[b * 2 + tid] = a;
    }
}

extern "C" void kernel_launch(void* const* d_in, const int* in_sizes, int n_in,
                              void* d_out, int out_size, void* d_ws, size_t ws_size,
                              hipStream_t stream) {
    const float* x    = (const float*)d_in[0];
    const float* Wi1  = (const float*)d_in[1];
    const float* bi1  = (const float*)d_in[2];
    const float* Whr1 = (const float*)d_in[3];
    const float* Whz1 = (const float*)d_in[4];
    const float* Whn1 = (const float*)d_in[5];
    const float* bhn1 = (const float*)d_in[6];
    const float* Wi2  = (const float*)d_in[7];
    const float* bi2  = (const float*)d_in[8];
    const float* Whr2 = (const float*)d_in[9];
    const float* Whz2 = (const float*)d_in[10];
    const float* Whn2 = (const float*)d_in[11];
    const float* bhn2 = (const float*)d_in[12];
    const float* Wp   = (const float*)d_in[13];
    const float* bp   = (const float*)d_in[14];
    const float* Wa   = (const float*)d_in[15];
    // d_in[16] = ba: softmax shift-invariant, unused
    const float* W1   = (const float*)d_in[17];
    const float* b1   = (const float*)d_in[18];
    const float* W2   = (const float*)d_in[19];
    const float* b2   = (const float*)d_in[20];
    const float* W3   = (const float*)d_in[21];
    const float* b3   = (const float*)d_in[22];
    const float* W4   = (const float*)d_in[23];
    const float* b4   = (const float*)d_in[24];

    solar_rnn<<<dim3(B_), dim3(256), 0, stream>>>(
        x, Wi1, bi1, Whr1, Whz1, Whn1, bhn1,
        Wi2, bi2, Whr2, Whz2, Whn2, bhn2,
        Wp, bp, Wa, W1, b1, W2, b2, W3, b3, W4, b4,
        (float*)d_out);
}